// Round 2
// baseline (311.662 us; speedup 1.0000x reference)
//
#include <hip/hip_runtime.h>

#define TPB 256
#define NWAVE (TPB / 64)

// Segment block-range ends (each segment start is a multiple of 8 so that
// blockIdx%8 == segment-local l%8, enabling XCD-steered half selection).
struct SegInfo {
    int e0, e1, e2, e3, e4;       // bond, angle, torsion, inversion, LJ ends
    int NB, NA, NT, NI, NC;
    int N;
};

__device__ __forceinline__ float clamp1(float x) {
    return fminf(fmaxf(x, -0.999999f), 0.999999f);
}

// Repack coords (B,N,3) -> cwA: float4[atom][4] (batches 0-3, 64B/atom)
//                          cwB: float4[atom][4] (batches 4-7, 64B/atom)
// Each half is 3.2 MB for N=50k -> fits a 4 MiB per-XCD L2.
// Also zeroes d_out (8 floats) so uff_kernel can atomicAdd.
__global__ void __launch_bounds__(TPB) transpose_coords(const float* __restrict__ coords,
                                                        float4* __restrict__ cwA,
                                                        float4* __restrict__ cwB,
                                                        float* __restrict__ out, int N) {
    const int b = blockIdx.y;                       // batch 0..7
    const int a = blockIdx.x * TPB + threadIdx.x;   // atom
    if (blockIdx.x == 0 && blockIdx.y == 0 && threadIdx.x < 8) out[threadIdx.x] = 0.f;
    if (a >= N) return;
    const float* s = coords + ((size_t)b * N + a) * 3;
    float4 v = make_float4(s[0], s[1], s[2], 0.f);
    float4* dst = (b < 4) ? cwA : cwB;
    dst[((size_t)a << 2) + (b & 3)] = v;
}

// Load one atom's 4 batch replicas (one half) as 4 float4s.
// USE_WS: packed 64B slot; else native (B,N,3) strided (bo = batch offset).
template <bool USE_WS>
__device__ __forceinline__ void load4(const float4* __restrict__ cws,
                                      const float* __restrict__ coords,
                                      int N, int bo, int atom, float4 v[4]) {
    if (USE_WS) {
        const float4* p = cws + ((size_t)atom << 2);
#pragma unroll
        for (int j = 0; j < 4; j++) v[j] = p[j];
    } else {
#pragma unroll
        for (int j = 0; j < 4; j++) {
            const float* sp = coords + ((size_t)(bo + j) * N + atom) * 3;
            v[j] = make_float4(sp[0], sp[1], sp[2], 0.f);
        }
    }
}

template <bool USE_WS>
__global__ void __launch_bounds__(TPB) uff_kernel(
    const float* __restrict__ coords,
    const float4* __restrict__ cwA, const float4* __restrict__ cwB,
    const int* __restrict__ bidx, const float* __restrict__ br0, const float* __restrict__ bk,
    const int* __restrict__ aidx, const float* __restrict__ ak,
    const float* __restrict__ ac0, const float* __restrict__ ac1, const float* __restrict__ ac2,
    const int* __restrict__ tidx, const float* __restrict__ tk,
    const int* __restrict__ tord, const float* __restrict__ tcos,
    const int* __restrict__ iidx, const float* __restrict__ ik,
    const float* __restrict__ ic0, const float* __restrict__ ic1, const float* __restrict__ ic2,
    const int* __restrict__ nidx, const float* __restrict__ vmin,
    const float* __restrict__ vdep, const float* __restrict__ vthr,
    float* __restrict__ out, SegInfo s)
{
    float acc[4];
#pragma unroll
    for (int b = 0; b < 4; b++) acc[b] = 0.f;

    const int blk = blockIdx.x;
    const int tid = threadIdx.x;
    const int N = s.N;

    // Segment decode + half-split. Blocks on XCDs 0-3 (blk%8 in 0..3) handle
    // batches 0-3 from cwA; XCDs 4-7 handle batches 4-7 from cwB. Each XCD's
    // gather working set is one 3.2 MB half -> L2-resident.
    int segStart, kind;
    if (blk < s.e0)      { segStart = 0;    kind = 0; }
    else if (blk < s.e1) { segStart = s.e0; kind = 1; }
    else if (blk < s.e2) { segStart = s.e1; kind = 2; }
    else if (blk < s.e3) { segStart = s.e2; kind = 3; }
    else                 { segStart = s.e3; kind = 4; }

    const int l = blk - segStart;
    const int xid = blk & 7;                    // == l & 7 (segStart % 8 == 0)
    const int half = (xid >> 2) & 1;
    const int t = (((l >> 3) << 2) + (xid & 3)) * TPB + tid;
    const float4* cws = half ? cwB : cwA;
    const int bo = half << 2;                   // batch offset 0 or 4

    if (kind == 0) {
        // ---------------- bond stretch ----------------
        if (t < s.NB) {
            const int2 ij = ((const int2*)bidx)[t];
            const float r0 = br0[t], k = bk[t];
            float4 ci[4], cj[4];
            load4<USE_WS>(cws, coords, N, bo, ij.x, ci);
            load4<USE_WS>(cws, coords, N, bo, ij.y, cj);
#pragma unroll
            for (int j = 0; j < 4; j++) {
                float dx = ci[j].x - cj[j].x, dy = ci[j].y - cj[j].y, dz = ci[j].z - cj[j].z;
                float dist = sqrtf(dx * dx + dy * dy + dz * dz);
                float dd = dist - r0;
                acc[j] += 0.5f * k * dd * dd;
            }
        }
    } else if (kind == 1) {
        // ---------------- angle bend ----------------
        if (t < s.NA) {
            const int i1 = aidx[3 * t], i2 = aidx[3 * t + 1], i3 = aidx[3 * t + 2];
            const float k = ak[t], c0 = ac0[t], c1 = ac1[t], c2 = ac2[t];
            float4 P[4], Q[4], R[4];
            load4<USE_WS>(cws, coords, N, bo, i1, P);
            load4<USE_WS>(cws, coords, N, bo, i2, Q);
            load4<USE_WS>(cws, coords, N, bo, i3, R);
#pragma unroll
            for (int j = 0; j < 4; j++) {
                float ax = P[j].x - Q[j].x, ay = P[j].y - Q[j].y, az = P[j].z - Q[j].z;
                float bx = R[j].x - Q[j].x, by = R[j].y - Q[j].y, bz = R[j].z - Q[j].z;
                float dot = ax * bx + ay * by + az * bz;
                float nn = (ax * ax + ay * ay + az * az) * (bx * bx + by * by + bz * bz);
                float ct = clamp1(dot * rsqrtf(fmaxf(nn, 1e-24f)));
                float cs = ct * ct;
                float ss = fmaxf(1.f - cs, 1e-12f);
                acc[j] += k * (c0 + c1 * ct + c2 * (cs - ss));
            }
        }
    } else if (kind == 2) {
        // ---------------- torsion ----------------
        if (t < s.NT) {
            const int4 q = ((const int4*)tidx)[t];
            const float V = tk[t], ctm = tcos[t];
            const int ord = tord[t];
            float4 P1[4], P2[4], P3[4], P4[4];
            load4<USE_WS>(cws, coords, N, bo, q.x, P1);
            load4<USE_WS>(cws, coords, N, bo, q.y, P2);
            load4<USE_WS>(cws, coords, N, bo, q.z, P3);
            load4<USE_WS>(cws, coords, N, bo, q.w, P4);
#pragma unroll
            for (int j = 0; j < 4; j++) {
                float b1x = P2[j].x - P1[j].x, b1y = P2[j].y - P1[j].y, b1z = P2[j].z - P1[j].z;
                float b2x = P3[j].x - P2[j].x, b2y = P3[j].y - P2[j].y, b2z = P3[j].z - P2[j].z;
                float b3x = P4[j].x - P3[j].x, b3y = P4[j].y - P3[j].y, b3z = P4[j].z - P3[j].z;
                float n1x = b1y * b2z - b1z * b2y;
                float n1y = b1z * b2x - b1x * b2z;
                float n1z = b1x * b2y - b1y * b2x;
                float n2x = b2y * b3z - b2z * b3y;
                float n2y = b2z * b3x - b2x * b3z;
                float n2z = b2x * b3y - b2y * b3x;
                float dot = n1x * n2x + n1y * n2y + n1z * n2z;
                float nn = (n1x * n1x + n1y * n1y + n1z * n1z) *
                           (n2x * n2x + n2y * n2y + n2z * n2z);
                float x = clamp1(dot * rsqrtf(fmaxf(nn, 1e-24f)));
                // cos(n*acos(x)) = T_n(x), n in [1,6]
                float Tp = 1.f, Tc = x, res = x;
#pragma unroll
                for (int kk = 2; kk <= 6; kk++) {
                    float Tn = 2.f * x * Tc - Tp;
                    Tp = Tc; Tc = Tn;
                    if (ord == kk) res = Tn;
                }
                acc[j] += 0.5f * V * (1.f - ctm * res);
            }
        }
    } else if (kind == 3) {
        // ---------------- inversion (Wilson) ----------------
        if (t < s.NI) {
            const int4 q = ((const int4*)iidx)[t];  // cols: i, central, k, l
            const float K = ik[t], c0 = ic0[t], c1 = ic1[t], c2 = ic2[t];
            float4 CA[4], PI[4], PK[4], PL[4];
            load4<USE_WS>(cws, coords, N, bo, q.y, CA);
            load4<USE_WS>(cws, coords, N, bo, q.x, PI);
            load4<USE_WS>(cws, coords, N, bo, q.z, PK);
            load4<USE_WS>(cws, coords, N, bo, q.w, PL);
#pragma unroll
            for (int j = 0; j < 4; j++) {
                float jix = PI[j].x - CA[j].x, jiy = PI[j].y - CA[j].y, jiz = PI[j].z - CA[j].z;
                float jkx = PK[j].x - CA[j].x, jky = PK[j].y - CA[j].y, jkz = PK[j].z - CA[j].z;
                float lx  = PL[j].x - CA[j].x, ly  = PL[j].y - CA[j].y, lz  = PL[j].z - CA[j].z;
                float nx = jiy * jkz - jiz * jky;
                float ny = jiz * jkx - jix * jkz;
                float nz = jix * jky - jiy * jkx;
                float dot = nx * lx + ny * ly + nz * lz;
                float nn = (nx * nx + ny * ny + nz * nz) * (lx * lx + ly * ly + lz * lz);
                float cosY = clamp1(dot * rsqrtf(fmaxf(nn, 1e-24f)));
                float sinY = sqrtf(fmaxf(1.f - cosY * cosY, 0.f));
                acc[j] += K * (c0 + c1 * sinY + c2 * (2.f * sinY * sinY - 1.f));
            }
        }
    } else {
        // ---------------- vdW LJ ----------------
        if (t < s.NC) {
            const int2 ij = ((const int2*)nidx)[t];
            const float R = vmin[t], D = vdep[t], thr = vthr[t];
            const float R2 = R * R;
            float4 ci[4], cj[4];
            load4<USE_WS>(cws, coords, N, bo, ij.x, ci);
            load4<USE_WS>(cws, coords, N, bo, ij.y, cj);
#pragma unroll
            for (int j = 0; j < 4; j++) {
                float dx = ci[j].x - cj[j].x, dy = ci[j].y - cj[j].y, dz = ci[j].z - cj[j].z;
                float d2 = dx * dx + dy * dy + dz * dz;
                float x2 = R2 / fmaxf(d2, 1e-12f);
                float x6 = x2 * x2 * x2;
                float e = D * (x6 * x6 - 2.f * x6);
                if (d2 <= thr) acc[j] += e;
            }
        }
    }

    // ---------------- block reduction: 4 batch sums (this half) ----------------
    __shared__ float red[NWAVE][4];
    const int lane = tid & 63;
    const int wid = tid >> 6;
#pragma unroll
    for (int b = 0; b < 4; b++) {
        float v = acc[b];
#pragma unroll
        for (int off = 32; off > 0; off >>= 1) v += __shfl_down(v, off, 64);
        if (lane == 0) red[wid][b] = v;
    }
    __syncthreads();
    if (tid < 4) {
        float ssum = 0.f;
#pragma unroll
        for (int w = 0; w < NWAVE; w++) ssum += red[w][tid];
        atomicAdd(&out[bo + tid], ssum);
    }
}

static inline int cdiv(int a, int b) { return (a + b - 1) / b; }
static inline int seglen(int n) { return (2 * cdiv(n, TPB) + 7) & ~7; }  // 2 halves, pad to %8

extern "C" void kernel_launch(void* const* d_in, const int* in_sizes, int n_in,
                              void* d_out, int out_size, void* d_ws, size_t ws_size,
                              hipStream_t stream) {
    const int B = out_size;  // expected 8
    const int NB = in_sizes[2], NA = in_sizes[5], NT = in_sizes[10],
              NI = in_sizes[14], NC = in_sizes[19];
    const int N = in_sizes[0] / (3 * B);

    const float* coords = (const float*)d_in[0];
    const int*   bidx = (const int*)d_in[1];
    const float* br0  = (const float*)d_in[2];
    const float* bk   = (const float*)d_in[3];
    const int*   aidx = (const int*)d_in[4];
    const float* ak   = (const float*)d_in[5];
    const float* ac0  = (const float*)d_in[6];
    const float* ac1  = (const float*)d_in[7];
    const float* ac2  = (const float*)d_in[8];
    const int*   tidx = (const int*)d_in[9];
    const float* tk   = (const float*)d_in[10];
    const int*   tord = (const int*)d_in[11];
    const float* tcos = (const float*)d_in[12];
    const int*   iidx = (const int*)d_in[13];
    const float* ik   = (const float*)d_in[14];
    const float* ic0  = (const float*)d_in[15];
    const float* ic1  = (const float*)d_in[16];
    const float* ic2  = (const float*)d_in[17];
    const int*   nidx = (const int*)d_in[18];
    const float* vmin = (const float*)d_in[19];
    const float* vdep = (const float*)d_in[20];
    const float* vthr = (const float*)d_in[21];

    const size_t ws_need = (size_t)N * 8 * sizeof(float4);
    const bool use_ws = ws_size >= ws_need;
    float4* cwA = (float4*)d_ws;
    float4* cwB = cwA + (size_t)N * 4;

    if (use_ws) {
        dim3 tg(cdiv(N, TPB), 8, 1);
        transpose_coords<<<tg, TPB, 0, stream>>>(coords, cwA, cwB, (float*)d_out, N);
    } else {
        hipMemsetAsync(d_out, 0, (size_t)out_size * sizeof(float), stream);
    }

    SegInfo s;
    s.NB = NB; s.NA = NA; s.NT = NT; s.NI = NI; s.NC = NC; s.N = N;
    s.e0 = seglen(NB);
    s.e1 = s.e0 + seglen(NA);
    s.e2 = s.e1 + seglen(NT);
    s.e3 = s.e2 + seglen(NI);
    s.e4 = s.e3 + seglen(NC);

    if (use_ws) {
        uff_kernel<true><<<s.e4, TPB, 0, stream>>>(
            coords, cwA, cwB, bidx, br0, bk, aidx, ak, ac0, ac1, ac2,
            tidx, tk, tord, tcos, iidx, ik, ic0, ic1, ic2,
            nidx, vmin, vdep, vthr, (float*)d_out, s);
    } else {
        uff_kernel<false><<<s.e4, TPB, 0, stream>>>(
            coords, cwA, cwB, bidx, br0, bk, aidx, ak, ac0, ac1, ac2,
            tidx, tk, tord, tcos, iidx, ik, ic0, ic1, ic2,
            nidx, vmin, vdep, vthr, (float*)d_out, s);
    }
}

// Round 3
// 197.580 us; speedup vs baseline: 1.5774x; 1.5774x over previous
//
#include <hip/hip_runtime.h>

#define TPB 256
#define NWAVE (TPB / 64)

typedef float vf4 __attribute__((ext_vector_type(4)));
typedef int   vi2 __attribute__((ext_vector_type(2)));
typedef int   vi4 __attribute__((ext_vector_type(4)));

struct SegInfo {
    int e0, e1, e2, e3, e4;       // block-range ends: bond, angle, torsion, inversion, LJ
    int NB, NA, NT, NI, NC;
    int N;
};

__device__ __forceinline__ float clamp1(float x) {
    return fminf(fmaxf(x, -0.999999f), 0.999999f);
}

__device__ __forceinline__ float ntf(const float* p) { return __builtin_nontemporal_load(p); }
__device__ __forceinline__ int   nti(const int* p)   { return __builtin_nontemporal_load(p); }

// Packed coord table: cw[atom*24 + b*3 + {0,1,2}] = xyz of batch b (96 B/atom, 16B-aligned).
// Load one atom's 8 batch replicas: 6 dwordx4 (vs 8 with float4 padding).
template <bool USE_WS>
__device__ __forceinline__ void loadA(const float* __restrict__ cw,
                                      const float* __restrict__ coords,
                                      int N, int atom, float c[24]) {
    if (USE_WS) {
        const vf4* p = (const vf4*)(cw + (size_t)atom * 24);
        vf4 t[6];
#pragma unroll
        for (int j = 0; j < 6; j++) t[j] = p[j];
#pragma unroll
        for (int j = 0; j < 6; j++) {
            c[4 * j] = t[j].x; c[4 * j + 1] = t[j].y;
            c[4 * j + 2] = t[j].z; c[4 * j + 3] = t[j].w;
        }
    } else {
#pragma unroll
        for (int b = 0; b < 8; b++) {
            const float* sp = coords + ((size_t)b * N + atom) * 3;
            c[3 * b] = sp[0]; c[3 * b + 1] = sp[1]; c[3 * b + 2] = sp[2];
        }
    }
}

// coords (B,N,3) -> cw float[atom][24]; also zeroes d_out.
__global__ void __launch_bounds__(TPB) transpose_coords(const float* __restrict__ coords,
                                                        float* __restrict__ cw,
                                                        float* __restrict__ out, int N) {
    const int a = blockIdx.x * TPB + threadIdx.x;
    if (blockIdx.x == 0 && threadIdx.x < 8) out[threadIdx.x] = 0.f;
    if (a >= N) return;
    float c[24];
#pragma unroll
    for (int b = 0; b < 8; b++) {
        const float* sp = coords + ((size_t)b * N + a) * 3;
        c[3 * b] = ntf(sp); c[3 * b + 1] = ntf(sp + 1); c[3 * b + 2] = ntf(sp + 2);
    }
    vf4* dst = (vf4*)(cw + (size_t)a * 24);
#pragma unroll
    for (int j = 0; j < 6; j++) {
        vf4 v;
        v.x = c[4 * j]; v.y = c[4 * j + 1]; v.z = c[4 * j + 2]; v.w = c[4 * j + 3];
        dst[j] = v;
    }
}

template <bool USE_WS>
__global__ void __launch_bounds__(TPB, 4) uff_kernel(
    const float* __restrict__ coords, const float* __restrict__ cw,
    const int* __restrict__ bidx, const float* __restrict__ br0, const float* __restrict__ bk,
    const int* __restrict__ aidx, const float* __restrict__ ak,
    const float* __restrict__ ac0, const float* __restrict__ ac1, const float* __restrict__ ac2,
    const int* __restrict__ tidx, const float* __restrict__ tk,
    const int* __restrict__ tord, const float* __restrict__ tcos,
    const int* __restrict__ iidx, const float* __restrict__ ik,
    const float* __restrict__ ic0, const float* __restrict__ ic1, const float* __restrict__ ic2,
    const int* __restrict__ nidx, const float* __restrict__ vmin,
    const float* __restrict__ vdep, const float* __restrict__ vthr,
    float* __restrict__ out, SegInfo s)
{
    float acc[8];
#pragma unroll
    for (int b = 0; b < 8; b++) acc[b] = 0.f;

    const int blk = blockIdx.x;
    const int tid = threadIdx.x;
    const int N = s.N;

    if (blk < s.e0) {
        // ---------------- bond stretch ----------------
        const int t = blk * TPB + tid;
        if (t < s.NB) {
            const vi2 ij = __builtin_nontemporal_load((const vi2*)bidx + t);
            const float r0 = ntf(br0 + t), k = ntf(bk + t);
            float ci[24], cj[24];
            loadA<USE_WS>(cw, coords, N, ij.x, ci);
            loadA<USE_WS>(cw, coords, N, ij.y, cj);
#pragma unroll
            for (int b = 0; b < 8; b++) {
                float dx = ci[3 * b] - cj[3 * b];
                float dy = ci[3 * b + 1] - cj[3 * b + 1];
                float dz = ci[3 * b + 2] - cj[3 * b + 2];
                float dd = sqrtf(dx * dx + dy * dy + dz * dz) - r0;
                acc[b] += 0.5f * k * dd * dd;
            }
        }
    } else if (blk < s.e1) {
        // ---------------- angle bend ----------------
        const int t = (blk - s.e0) * TPB + tid;
        if (t < s.NA) {
            const int i1 = nti(aidx + 3 * t), i2 = nti(aidx + 3 * t + 1), i3 = nti(aidx + 3 * t + 2);
            const float k = ntf(ak + t), c0 = ntf(ac0 + t), c1 = ntf(ac1 + t), c2 = ntf(ac2 + t);
            float P[24], Q[24], R[24];
            loadA<USE_WS>(cw, coords, N, i1, P);
            loadA<USE_WS>(cw, coords, N, i2, Q);
            loadA<USE_WS>(cw, coords, N, i3, R);
#pragma unroll
            for (int b = 0; b < 8; b++) {
                float ax = P[3 * b] - Q[3 * b], ay = P[3 * b + 1] - Q[3 * b + 1], az = P[3 * b + 2] - Q[3 * b + 2];
                float bx = R[3 * b] - Q[3 * b], by = R[3 * b + 1] - Q[3 * b + 1], bz = R[3 * b + 2] - Q[3 * b + 2];
                float dot = ax * bx + ay * by + az * bz;
                float nn = (ax * ax + ay * ay + az * az) * (bx * bx + by * by + bz * bz);
                float ct = clamp1(dot * rsqrtf(fmaxf(nn, 1e-24f)));
                float cs = ct * ct;
                float ss = fmaxf(1.f - cs, 1e-12f);
                acc[b] += k * (c0 + c1 * ct + c2 * (cs - ss));
            }
        }
    } else if (blk < s.e2) {
        // ---------------- torsion ----------------
        const int t = (blk - s.e1) * TPB + tid;
        if (t < s.NT) {
            const vi4 q = __builtin_nontemporal_load((const vi4*)tidx + t);
            const float V = ntf(tk + t), ctm = ntf(tcos + t);
            const int ord = nti(tord + t);
            float P1[24], P2[24], P3[24], P4[24];
            loadA<USE_WS>(cw, coords, N, q.x, P1);
            loadA<USE_WS>(cw, coords, N, q.y, P2);
            loadA<USE_WS>(cw, coords, N, q.z, P3);
            loadA<USE_WS>(cw, coords, N, q.w, P4);
#pragma unroll
            for (int b = 0; b < 8; b++) {
                float b1x = P2[3 * b] - P1[3 * b], b1y = P2[3 * b + 1] - P1[3 * b + 1], b1z = P2[3 * b + 2] - P1[3 * b + 2];
                float b2x = P3[3 * b] - P2[3 * b], b2y = P3[3 * b + 1] - P2[3 * b + 1], b2z = P3[3 * b + 2] - P2[3 * b + 2];
                float b3x = P4[3 * b] - P3[3 * b], b3y = P4[3 * b + 1] - P3[3 * b + 1], b3z = P4[3 * b + 2] - P3[3 * b + 2];
                float n1x = b1y * b2z - b1z * b2y;
                float n1y = b1z * b2x - b1x * b2z;
                float n1z = b1x * b2y - b1y * b2x;
                float n2x = b2y * b3z - b2z * b3y;
                float n2y = b2z * b3x - b2x * b3z;
                float n2z = b2x * b3y - b2y * b3x;
                float dot = n1x * n2x + n1y * n2y + n1z * n2z;
                float nn = (n1x * n1x + n1y * n1y + n1z * n1z) *
                           (n2x * n2x + n2y * n2y + n2z * n2z);
                float x = clamp1(dot * rsqrtf(fmaxf(nn, 1e-24f)));
                // cos(n*acos(x)) = T_n(x), n in [1,6]
                float Tp = 1.f, Tc = x, res = x;
#pragma unroll
                for (int kk = 2; kk <= 6; kk++) {
                    float Tn = 2.f * x * Tc - Tp;
                    Tp = Tc; Tc = Tn;
                    if (ord == kk) res = Tn;
                }
                acc[b] += 0.5f * V * (1.f - ctm * res);
            }
        }
    } else if (blk < s.e3) {
        // ---------------- inversion (Wilson) ----------------
        const int t = (blk - s.e2) * TPB + tid;
        if (t < s.NI) {
            const vi4 q = __builtin_nontemporal_load((const vi4*)iidx + t);  // i, central, k, l
            const float K = ntf(ik + t), c0 = ntf(ic0 + t), c1 = ntf(ic1 + t), c2 = ntf(ic2 + t);
            float CA[24], PI[24], PK[24], PL[24];
            loadA<USE_WS>(cw, coords, N, q.y, CA);
            loadA<USE_WS>(cw, coords, N, q.x, PI);
            loadA<USE_WS>(cw, coords, N, q.z, PK);
            loadA<USE_WS>(cw, coords, N, q.w, PL);
#pragma unroll
            for (int b = 0; b < 8; b++) {
                float jix = PI[3 * b] - CA[3 * b], jiy = PI[3 * b + 1] - CA[3 * b + 1], jiz = PI[3 * b + 2] - CA[3 * b + 2];
                float jkx = PK[3 * b] - CA[3 * b], jky = PK[3 * b + 1] - CA[3 * b + 1], jkz = PK[3 * b + 2] - CA[3 * b + 2];
                float lx  = PL[3 * b] - CA[3 * b], ly  = PL[3 * b + 1] - CA[3 * b + 1], lz  = PL[3 * b + 2] - CA[3 * b + 2];
                float nx = jiy * jkz - jiz * jky;
                float ny = jiz * jkx - jix * jkz;
                float nz = jix * jky - jiy * jkx;
                float dot = nx * lx + ny * ly + nz * lz;
                float nn = (nx * nx + ny * ny + nz * nz) * (lx * lx + ly * ly + lz * lz);
                float cosY = clamp1(dot * rsqrtf(fmaxf(nn, 1e-24f)));
                float sinY = sqrtf(fmaxf(1.f - cosY * cosY, 0.f));
                acc[b] += K * (c0 + c1 * sinY + c2 * (2.f * sinY * sinY - 1.f));
            }
        }
    } else {
        // ---------------- vdW LJ: 2 pairs per thread ----------------
        const int t0 = (blk - s.e3) * (2 * TPB) + tid;
        const int t1 = t0 + TPB;
        const bool v0 = t0 < s.NC, v1 = t1 < s.NC;
        // Hoist both pairs' indices/params so gathers for pair1 can overlap pair0 compute.
        vi2 ij0, ij1;
        float R0 = 0.f, D0 = 0.f, th0 = 0.f, R1 = 0.f, D1 = 0.f, th1 = 0.f;
        if (v0) {
            ij0 = __builtin_nontemporal_load((const vi2*)nidx + t0);
            R0 = ntf(vmin + t0); D0 = ntf(vdep + t0); th0 = ntf(vthr + t0);
        }
        if (v1) {
            ij1 = __builtin_nontemporal_load((const vi2*)nidx + t1);
            R1 = ntf(vmin + t1); D1 = ntf(vdep + t1); th1 = ntf(vthr + t1);
        }
        if (v0) {
            float ci[24], cj[24];
            loadA<USE_WS>(cw, coords, N, ij0.x, ci);
            loadA<USE_WS>(cw, coords, N, ij0.y, cj);
            const float R2 = R0 * R0;
#pragma unroll
            for (int b = 0; b < 8; b++) {
                float dx = ci[3 * b] - cj[3 * b];
                float dy = ci[3 * b + 1] - cj[3 * b + 1];
                float dz = ci[3 * b + 2] - cj[3 * b + 2];
                float d2 = dx * dx + dy * dy + dz * dz;
                float x2 = R2 / fmaxf(d2, 1e-12f);
                float x6 = x2 * x2 * x2;
                float e = D0 * (x6 * x6 - 2.f * x6);
                if (d2 <= th0) acc[b] += e;
            }
        }
        if (v1) {
            float ci[24], cj[24];
            loadA<USE_WS>(cw, coords, N, ij1.x, ci);
            loadA<USE_WS>(cw, coords, N, ij1.y, cj);
            const float R2 = R1 * R1;
#pragma unroll
            for (int b = 0; b < 8; b++) {
                float dx = ci[3 * b] - cj[3 * b];
                float dy = ci[3 * b + 1] - cj[3 * b + 1];
                float dz = ci[3 * b + 2] - cj[3 * b + 2];
                float d2 = dx * dx + dy * dy + dz * dz;
                float x2 = R2 / fmaxf(d2, 1e-12f);
                float x6 = x2 * x2 * x2;
                float e = D1 * (x6 * x6 - 2.f * x6);
                if (d2 <= th1) acc[b] += e;
            }
        }
    }

    // ---------------- block reduction: 8 batch sums ----------------
    __shared__ float red[NWAVE][8];
    const int lane = tid & 63;
    const int wid = tid >> 6;
#pragma unroll
    for (int b = 0; b < 8; b++) {
        float v = acc[b];
#pragma unroll
        for (int off = 32; off > 0; off >>= 1) v += __shfl_down(v, off, 64);
        if (lane == 0) red[wid][b] = v;
    }
    __syncthreads();
    if (tid < 8) {
        float ssum = 0.f;
#pragma unroll
        for (int w = 0; w < NWAVE; w++) ssum += red[w][tid];
        atomicAdd(&out[tid], ssum);
    }
}

static inline int cdiv(int a, int b) { return (a + b - 1) / b; }

extern "C" void kernel_launch(void* const* d_in, const int* in_sizes, int n_in,
                              void* d_out, int out_size, void* d_ws, size_t ws_size,
                              hipStream_t stream) {
    const int B = out_size;  // expected 8 (kernel hard-codes 8 batch accumulators)
    const int NB = in_sizes[2], NA = in_sizes[5], NT = in_sizes[10],
              NI = in_sizes[14], NC = in_sizes[19];
    const int N = in_sizes[0] / (3 * B);

    const float* coords = (const float*)d_in[0];
    const int*   bidx = (const int*)d_in[1];
    const float* br0  = (const float*)d_in[2];
    const float* bk   = (const float*)d_in[3];
    const int*   aidx = (const int*)d_in[4];
    const float* ak   = (const float*)d_in[5];
    const float* ac0  = (const float*)d_in[6];
    const float* ac1  = (const float*)d_in[7];
    const float* ac2  = (const float*)d_in[8];
    const int*   tidx = (const int*)d_in[9];
    const float* tk   = (const float*)d_in[10];
    const int*   tord = (const int*)d_in[11];
    const float* tcos = (const float*)d_in[12];
    const int*   iidx = (const int*)d_in[13];
    const float* ik   = (const float*)d_in[14];
    const float* ic0  = (const float*)d_in[15];
    const float* ic1  = (const float*)d_in[16];
    const float* ic2  = (const float*)d_in[17];
    const int*   nidx = (const int*)d_in[18];
    const float* vmin = (const float*)d_in[19];
    const float* vdep = (const float*)d_in[20];
    const float* vthr = (const float*)d_in[21];

    const size_t ws_need = (size_t)N * 24 * sizeof(float);
    const bool use_ws = ws_size >= ws_need;
    float* cwp = (float*)d_ws;

    if (use_ws) {
        transpose_coords<<<cdiv(N, TPB), TPB, 0, stream>>>(coords, cwp, (float*)d_out, N);
    } else {
        hipMemsetAsync(d_out, 0, (size_t)out_size * sizeof(float), stream);
    }

    SegInfo s;
    s.NB = NB; s.NA = NA; s.NT = NT; s.NI = NI; s.NC = NC; s.N = N;
    s.e0 = cdiv(NB, TPB);
    s.e1 = s.e0 + cdiv(NA, TPB);
    s.e2 = s.e1 + cdiv(NT, TPB);
    s.e3 = s.e2 + cdiv(NI, TPB);
    s.e4 = s.e3 + cdiv(NC, 2 * TPB);

    if (use_ws) {
        uff_kernel<true><<<s.e4, TPB, 0, stream>>>(
            coords, cwp, bidx, br0, bk, aidx, ak, ac0, ac1, ac2,
            tidx, tk, tord, tcos, iidx, ik, ic0, ic1, ic2,
            nidx, vmin, vdep, vthr, (float*)d_out, s);
    } else {
        uff_kernel<false><<<s.e4, TPB, 0, stream>>>(
            coords, cwp, bidx, br0, bk, aidx, ak, ac0, ac1, ac2,
            tidx, tk, tord, tcos, iidx, ik, ic0, ic1, ic2,
            nidx, vmin, vdep, vthr, (float*)d_out, s);
    }
}